// Round 2
// baseline (221.400 us; speedup 1.0000x reference)
//
#include <hip/hip_runtime.h>

// MinVarianceWeightsLayer: for each of B SPD 64x64 fp32 matrices S,
// solve S z = 1, output w = z / sum(z) as [B, 64, 1] fp32.
//
// One wave per matrix, lane i owns row i in VGPRs (64 floats). Gaussian
// elimination without pivoting (stable for SPD), fully unrolled; pivot-row
// broadcast via v_readlane (constant lane index) -> zero LDS traffic.
//
// __launch_bounds__(256, 1): min 1 wave/EU frees the register allocator to
// keep row[64] in ARCH VGPRs. Round-1 evidence: default heuristic capped at
// 68 VGPRs and spilled row[] to AGPRs (VGPR_Count=68, no scratch traffic),
// turning the 2-op inner loop (readlane+fmac) into a 4-op one
// (accvgpr_read+readlane+fma+accvgpr_write) -> measured 95us, VALUBusy 67%.

#define NN 64

__device__ __forceinline__ float rlane(float v, int lane) {
    return __int_as_float(__builtin_amdgcn_readlane(__float_as_int(v), lane));
}

__device__ __forceinline__ float frcp(float x) {
#if __has_builtin(__builtin_amdgcn_rcpf)
    return __builtin_amdgcn_rcpf(x);   // ~1 ulp; plenty vs 2e-3 abs threshold
#else
    return 1.0f / x;
#endif
}

__global__ __launch_bounds__(256, 1) void minvar_kernel(const float* __restrict__ sigma,
                                                        float* __restrict__ out,
                                                        int batch) {
    const int lane = threadIdx.x & 63;
    const int wid  = threadIdx.x >> 6;     // 4 waves per block, 1 matrix each
    const int bid  = blockIdx.x * 4 + wid;
    if (bid >= batch) return;

    const float* __restrict__ p = sigma + (size_t)bid * (NN * NN) + (size_t)lane * NN;

    // Load own row (contiguous per lane). Input is L3-resident after first
    // touch (134 MB < 256 MB Infinity Cache) -> kernel is pure-VALU-bound.
    float row[NN];
    #pragma unroll
    for (int j4 = 0; j4 < NN / 4; ++j4) {
        float4 v = reinterpret_cast<const float4*>(p)[j4];
        row[4 * j4 + 0] = v.x;
        row[4 * j4 + 1] = v.y;
        row[4 * j4 + 2] = v.z;
        row[4 * j4 + 3] = v.w;
    }

    float b = 1.0f;   // RHS: ones

    // ---- Forward elimination: row_i -= (S[i][k]/S[k][k]) * row_k, i > k ----
    // Lanes i <= k get factor 0 (wave-uniform no-op) so rows stay lockstep.
    #pragma unroll
    for (int k = 0; k < NN; ++k) {
        const float pivot = rlane(row[k], k);       // current S[k][k]
        const float invp  = frcp(pivot);
        const float nf    = (lane > k) ? (-row[k] * invp) : 0.0f;
        const float bk    = rlane(b, k);
        b = fmaf(nf, bk, b);
        #pragma unroll
        for (int j = k + 1; j < NN; ++j) {
            const float bc = rlane(row[j], k);      // pivot-row element -> SGPR
            row[j] = fmaf(nf, bc, row[j]);          // v_fmac with SGPR operand
        }
    }

    // ---- Back substitution: U z = y (U[i][j] = row[j] on lane i, j >= i) ----
    #pragma unroll
    for (int k = NN - 1; k >= 0; --k) {
        const float ukk = rlane(row[k], k);
        const float yk  = rlane(b, k);
        const float zk  = yk * frcp(ukk);
        const float upd = (lane < k) ? (-row[k]) : 0.0f;
        b = fmaf(upd, zk, b);       // eliminate column k from rows above
        if (lane == k) b = zk;      // lane k's solution is final
    }

    // ---- Normalize: w = z / sum(z) ----
    float total = b;
    #pragma unroll
    for (int off = 32; off >= 1; off >>= 1)
        total += __shfl_xor(total, off, 64);

    out[(size_t)bid * NN + lane] = b * frcp(total);
}

extern "C" void kernel_launch(void* const* d_in, const int* in_sizes, int n_in,
                              void* d_out, int out_size, void* d_ws, size_t ws_size,
                              hipStream_t stream) {
    const float* sigma = (const float*)d_in[0];
    float* out = (float*)d_out;
    const int batch = in_sizes[0] / (NN * NN);      // 8192
    const int blocks = (batch + 3) / 4;             // 4 matrices per 256-thr block
    minvar_kernel<<<blocks, 256, 0, stream>>>(sigma, out, batch);
}

// Round 3
// 220.707 us; speedup vs baseline: 1.0031x; 1.0031x over previous
//
#include <hip/hip_runtime.h>

// MinVarianceWeightsLayer: for each of B SPD 64x64 fp32 matrices S,
// solve S z = 1, output w = z / sum(z) as [B, 64, 1] fp32.
//
// One wave per matrix, lane i owns row i in VGPRs (64 floats). Gaussian
// elimination without pivoting (stable for SPD: eig(S) in [0.1, ~4.5]).
//
// ROUND-2 LESSON: #pragma unroll on the 64-iter outer loop (with variable-trip
// inner loop) was DECLINED by the compiler -> row[] became a dynamically
// indexed register array accessed via v_movrel (VGPR_Count=68 = 64 row + 4
// temps, ~4 VALU ops/element, 95us). Fix: template-recursion static unroll so
// every index (row[] subscript AND readlane lane) is a compile-time constant.
// Inner element = v_readlane_b32 + v_fmac_f32(sgpr) = 2 VALU ops.

#define NN 64

template <int I> struct ic { static constexpr int value = I; };

template <int Start, int End, typename F>
__device__ __forceinline__ void static_for(F&& f) {
    if constexpr (Start < End) {
        f(ic<Start>{});
        static_for<Start + 1, End>(static_cast<F&&>(f));
    }
}

__device__ __forceinline__ float rlane(float v, int lane) {
    return __int_as_float(__builtin_amdgcn_readlane(__float_as_int(v), lane));
}

__device__ __forceinline__ float frcp(float x) {
#if __has_builtin(__builtin_amdgcn_rcpf)
    return __builtin_amdgcn_rcpf(x);   // ~1 ulp; plenty vs 2e-3 abs threshold
#else
    return 1.0f / x;
#endif
}

__global__ __launch_bounds__(256, 1) void minvar_kernel(const float* __restrict__ sigma,
                                                        float* __restrict__ out,
                                                        int batch) {
    const int lane = threadIdx.x & 63;
    const int wid  = threadIdx.x >> 6;     // 4 waves per block, 1 matrix each
    const int bid  = blockIdx.x * 4 + wid;
    if (bid >= batch) return;

    const float* __restrict__ p = sigma + (size_t)bid * (NN * NN) + (size_t)lane * NN;

    // Own row, fully scalar-promoted (all indices below are compile-time).
    float row[NN];
    static_for<0, NN / 4>([&](auto j4c) {
        constexpr int j4 = decltype(j4c)::value;
        float4 v = reinterpret_cast<const float4*>(p)[j4];
        row[4 * j4 + 0] = v.x;
        row[4 * j4 + 1] = v.y;
        row[4 * j4 + 2] = v.z;
        row[4 * j4 + 3] = v.w;
    });

    float b = 1.0f;   // RHS: ones

    // ---- Forward elimination: row_i -= (S[i][k]/S[k][k]) * row_k, i > k ----
    // Lanes i <= k get factor 0 (wave-uniform no-op) so rows stay lockstep.
    static_for<0, NN>([&](auto kc) {
        constexpr int k = decltype(kc)::value;
        const float pivot = rlane(row[k], k);       // current S[k][k] -> SGPR
        const float invp  = frcp(pivot);
        const float nf    = (lane > k) ? (-row[k] * invp) : 0.0f;
        b = fmaf(nf, rlane(b, k), b);
        static_for<k + 1, NN>([&](auto jc) {
            constexpr int j = decltype(jc)::value;
            row[j] = fmaf(nf, rlane(row[j], k), row[j]);  // readlane + fmac
        });
    });

    // ---- Back substitution: U z = y (U[i][j] = row[j] on lane i, j >= i) ----
    static_for<0, NN>([&](auto kk) {
        constexpr int k = NN - 1 - decltype(kk)::value;
        const float ukk = rlane(row[k], k);
        const float yk  = rlane(b, k);
        const float zk  = yk * frcp(ukk);
        const float upd = (lane < k) ? (-row[k]) : 0.0f;
        b = fmaf(upd, zk, b);       // eliminate column k from rows above
        if (lane == k) b = zk;      // lane k's solution is final
    });

    // ---- Normalize: w = z / sum(z) ----
    float total = b;
    #pragma unroll
    for (int off = 32; off >= 1; off >>= 1)
        total += __shfl_xor(total, off, 64);

    out[(size_t)bid * NN + lane] = b * frcp(total);
}

extern "C" void kernel_launch(void* const* d_in, const int* in_sizes, int n_in,
                              void* d_out, int out_size, void* d_ws, size_t ws_size,
                              hipStream_t stream) {
    const float* sigma = (const float*)d_in[0];
    float* out = (float*)d_out;
    const int batch = in_sizes[0] / (NN * NN);      // 8192
    const int blocks = (batch + 3) / 4;             // 4 matrices per 256-thr block
    minvar_kernel<<<blocks, 256, 0, stream>>>(sigma, out, batch);
}

// Round 4
// 204.618 us; speedup vs baseline: 1.0820x; 1.0786x over previous
//
#include <hip/hip_runtime.h>

// MinVarianceWeightsLayer: for each of B SPD 64x64 fp32 matrices S,
// solve S z = 1, output w = z / sum(z) as [B, 64, 1] fp32.
//
// One wave per matrix, lane i owns row i in VGPRs as 32 float2 pairs.
// Gaussian elimination without pivoting (SPD, kappa~41 -> stable).
//
// ROUND-3 LESSON: rounds 1-3 all compiled to the same unrolled code
// (VGPR=68=64+4, SGPR=16) at 95us -- ~2x slower than the 2-instr/elem model.
// Suspected: v_readlane(SGPR write) -> v_fmac(SGPR read) scheduled
// back-to-back (only 16 SGPRs!) exposes the VALU-SGPR hazard every element.
// ROUND-4 FIX: (a) float2 rows + v_pk_fma_f32: 2 readlanes + 1 pk_fma per
// 2 elements (1.5 instr/elem); (b) batch 4 pairs of readlanes into explicit
// uniform temporaries (SGPR pairs) before the 4 pk_fmas -> 4-8 instr of
// scheduling distance to hide the SGPR-write hazard.

#define NN 64

typedef float v2f __attribute__((ext_vector_type(2)));

template <int I> struct ic { static constexpr int value = I; };

template <int Start, int End, typename F>
__device__ __forceinline__ void static_for(F&& f) {
    if constexpr (Start < End) {
        f(ic<Start>{});
        static_for<Start + 1, End>(static_cast<F&&>(f));
    }
}

__device__ __forceinline__ float rlane(float v, int lane) {
    return __int_as_float(__builtin_amdgcn_readlane(__float_as_int(v), lane));
}

__device__ __forceinline__ float frcp(float x) {
#if __has_builtin(__builtin_amdgcn_rcpf)
    return __builtin_amdgcn_rcpf(x);   // ~1 ulp; plenty vs 2e-3 abs threshold
#else
    return 1.0f / x;
#endif
}

__device__ __forceinline__ v2f fma2(v2f a, v2f b, v2f c) {
#if __has_builtin(__builtin_elementwise_fma)
    return __builtin_elementwise_fma(a, b, c);   // -> v_pk_fma_f32
#else
    v2f r; r.x = fmaf(a.x, b.x, c.x); r.y = fmaf(a.y, b.y, c.y); return r;
#endif
}

__global__ __launch_bounds__(256, 1) void minvar_kernel(const float* __restrict__ sigma,
                                                        float* __restrict__ out,
                                                        int batch) {
    const int lane = threadIdx.x & 63;
    const int wid  = threadIdx.x >> 6;     // 4 waves per block, 1 matrix each
    const int bid  = blockIdx.x * 4 + wid;
    if (bid >= batch) return;

    const float* __restrict__ p = sigma + (size_t)bid * (NN * NN) + (size_t)lane * NN;

    // Own row as 32 float2 pairs (all indices compile-time -> SROA to VGPRs).
    v2f r[NN / 2];
    static_for<0, NN / 4>([&](auto j4c) {
        constexpr int j4 = decltype(j4c)::value;
        float4 v = reinterpret_cast<const float4*>(p)[j4];
        r[2 * j4 + 0] = v2f{v.x, v.y};
        r[2 * j4 + 1] = v2f{v.z, v.w};
    });

    float b = 1.0f;   // RHS: ones

    // ---- Forward elimination: row_i -= (S[i][k]/S[k][k]) * row_k, i > k ----
    static_for<0, NN>([&](auto kc) {
        constexpr int k  = decltype(kc)::value;
        constexpr int pk = k / 2;
        const float ekk  = (k & 1) ? r[pk].y : r[pk].x;   // lane's element k
        const float pivot = rlane(ekk, k);                // S[k][k] (uniform)
        const float invp  = frcp(pivot);
        const float nf    = (lane > k) ? (-ekk * invp) : 0.0f;
        const v2f   nf2   = v2f{nf, nf};
        b = fmaf(nf, rlane(b, k), b);

        // odd leading element (k even: j=k+1 is .y of pair pk)
        if constexpr ((k & 1) == 0) {
            const float bcy = rlane(r[pk].y, k);
            r[pk].y = fmaf(nf, bcy, r[pk].y);
        }

        // full pairs, batched 4-at-a-time: readlanes first, then pk_fmas
        constexpr int P0 = pk + 1;
        static_for<0, (NN / 2 - P0 + 3) / 4>([&](auto gc) {
            constexpr int g0 = P0 + 4 * decltype(gc)::value;
            v2f bc[4];
            static_for<0, 4>([&](auto tc) {
                constexpr int t = decltype(tc)::value;
                if constexpr (g0 + t < NN / 2)
                    bc[t] = v2f{rlane(r[g0 + t].x, k), rlane(r[g0 + t].y, k)};
            });
            static_for<0, 4>([&](auto tc) {
                constexpr int t = decltype(tc)::value;
                if constexpr (g0 + t < NN / 2)
                    r[g0 + t] = fma2(nf2, bc[t], r[g0 + t]);
            });
        });
    });

    // ---- Back substitution: U z = y (U[i][j] = r[...][j] on lane i) ----
    static_for<0, NN>([&](auto kk) {
        constexpr int k  = NN - 1 - decltype(kk)::value;
        constexpr int pk = k / 2;
        const float ekk  = (k & 1) ? r[pk].y : r[pk].x;
        const float ukk  = rlane(ekk, k);
        const float yk   = rlane(b, k);
        const float zk   = yk * frcp(ukk);
        const float upd  = (lane < k) ? (-ekk) : 0.0f;
        b = (lane == k) ? zk : fmaf(upd, zk, b);
    });

    // ---- Normalize: w = z / sum(z) ----
    float total = b;
    #pragma unroll
    for (int off = 32; off >= 1; off >>= 1)
        total += __shfl_xor(total, off, 64);

    out[(size_t)bid * NN + lane] = b * frcp(total);
}

extern "C" void kernel_launch(void* const* d_in, const int* in_sizes, int n_in,
                              void* d_out, int out_size, void* d_ws, size_t ws_size,
                              hipStream_t stream) {
    const float* sigma = (const float*)d_in[0];
    float* out = (float*)d_out;
    const int batch = in_sizes[0] / (NN * NN);      // 8192
    const int blocks = (batch + 3) / 4;             // 4 matrices per 256-thr block
    minvar_kernel<<<blocks, 256, 0, stream>>>(sigma, out, batch);
}